// Round 3
// baseline (1283.567 us; speedup 1.0000x reference)
//
#include <hip/hip_runtime.h>
#include <hip/hip_bf16.h>

#define N_ 768
#define CS 384
#define CZ 128
#define HH 12
#define PQ_ 4
#define PV_ 8

// ---------------------------------------------------------------------------
// K1: projections per residue n. (all fp32)
// raw[0:192]   = q rows
// raw[192:576] = kv rows (h*32 + c; c<16 -> k, else v)
// raw[576:720] = q_pts proj (coord*48 + hp), hp = h*4+p
// raw[720:1152]= kv_pts proj (coord*144 + j), j = h*12+p (p<4 k_pts else v_pts)
// ---------------------------------------------------------------------------
__global__ __launch_bounds__(256) void k_proj(
    const float* __restrict__ s,
    const float* __restrict__ rot,
    const float* __restrict__ trans,
    const float* __restrict__ w_q,  const float* __restrict__ b_q,
    const float* __restrict__ w_kv, const float* __restrict__ b_kv,
    const float* __restrict__ w_qp, const float* __restrict__ b_qp,
    const float* __restrict__ w_kvp,const float* __restrict__ b_kvp,
    float* __restrict__ q, float* __restrict__ k, float* __restrict__ v,
    float* __restrict__ qp, float* __restrict__ kp, float* __restrict__ vp)
{
    const int n   = blockIdx.x;
    const int tid = threadIdx.x;
    __shared__ float s_sh[CS];
    __shared__ float raw[1152];
    __shared__ float R[9], T[3];

    for (int i = tid; i < CS; i += 256) s_sh[i] = s[n * CS + i];
    if (tid < 9) R[tid] = rot[n * 9 + tid];
    if (tid < 3) T[tid] = trans[n * 3 + tid];
    __syncthreads();

    for (int idx = tid; idx < 1152; idx += 256) {
        const float* wrow;
        float bias;
        if (idx < 192)      { wrow = w_q + idx * CS;               bias = b_q[idx]; }
        else if (idx < 576) { int r = idx - 192; wrow = w_kv + r * CS;  bias = b_kv[r]; }
        else if (idx < 720) { int r = idx - 576; wrow = w_qp + r * CS;  bias = b_qp[r]; }
        else                { int r = idx - 720; wrow = w_kvp + r * CS; bias = b_kvp[r]; }
        float acc = bias;
        const float4* w4 = (const float4*)wrow;
        #pragma unroll 4
        for (int c4 = 0; c4 < CS / 4; ++c4) {
            float4 wv = w4[c4];
            const float* sp = &s_sh[c4 * 4];
            acc += sp[0] * wv.x + sp[1] * wv.y + sp[2] * wv.z + sp[3] * wv.w;
        }
        raw[idx] = acc;
    }
    __syncthreads();

    for (int i = tid; i < 192; i += 256) {
        q[n * 192 + i] = raw[i];
        int h = i >> 4, c = i & 15;
        k[n * 192 + i] = raw[192 + h * 32 + c];
        v[n * 192 + i] = raw[192 + h * 32 + 16 + c];
    }
    for (int hp = tid; hp < 48; hp += 256) {
        float x = raw[576 + hp], y = raw[576 + 48 + hp], zc = raw[576 + 96 + hp];
        #pragma unroll
        for (int i = 0; i < 3; ++i)
            qp[n * 144 + hp * 3 + i] = R[i * 3 + 0] * x + R[i * 3 + 1] * y + R[i * 3 + 2] * zc + T[i];
    }
    for (int j = tid; j < 144; j += 256) {
        float x = raw[720 + j], y = raw[720 + 144 + j], zc = raw[720 + 288 + j];
        float p0 = R[0] * x + R[1] * y + R[2] * zc + T[0];
        float p1 = R[3] * x + R[4] * y + R[5] * zc + T[1];
        float p2 = R[6] * x + R[7] * y + R[8] * zc + T[2];
        int h = j / 12, p = j % 12;
        if (p < PQ_) {
            int o = n * 144 + (h * PQ_ + p) * 3;
            kp[o] = p0; kp[o + 1] = p1; kp[o + 2] = p2;
        } else {
            int o = n * 288 + (h * PV_ + (p - PQ_)) * 3;
            vp[o] = p0; vp[o + 1] = p1; vp[o + 2] = p2;
        }
    }
}

// ---------------------------------------------------------------------------
// K2 (fused): per residue n — z bias projection, logits, softmax (probs kept
// in LDS), then o = a@v, o_pt (+inv rot, norms), o_pair = a@z.
// Writes o_cat[n][2112] = [o(192) | x(96) | y(96) | z(96) | norm(96) | pair(1536)]
// ---------------------------------------------------------------------------
__global__ __launch_bounds__(256) void k_fused(
    const float* __restrict__ q, const float* __restrict__ k,
    const float* __restrict__ v,
    const float* __restrict__ qp, const float* __restrict__ kp,
    const float* __restrict__ vp,
    const float* __restrict__ z,
    const float* __restrict__ w_b, const float* __restrict__ b_b,
    const float* __restrict__ head_weights,
    const float* __restrict__ mask,
    const float* __restrict__ rot, const float* __restrict__ trans,
    float* __restrict__ ocat)
{
    const int n   = blockIdx.x;
    const int tid = threadIdx.x;

    __shared__ float qv[192], qpt[144];
    __shared__ float wb[HH * CZ];            // 6 KB
    __shared__ float bb[HH], hw[HH];
    __shared__ float L[HH * N_];             // 36 KB: logits -> probs
    __shared__ float og[288];
    __shared__ float part[2 * HH * CZ];      // 12 KB
    __shared__ float R[9], T[3];

    for (int i = tid; i < 192; i += 256) qv[i] = q[n * 192 + i];
    for (int i = tid; i < 144; i += 256) qpt[i] = qp[n * 144 + i];
    for (int i = tid; i < HH * CZ; i += 256) wb[i] = w_b[i];
    if (tid < HH) {
        bb[tid] = b_b[tid];
        float x = head_weights[tid];
        // softplus(x) * sqrt(1/(3*(PQ*9/2)))
        hw[tid] = 0.13608276348795434f * logf(1.0f + expf(x));
    }
    if (tid < 9) R[tid] = rot[n * 9 + tid];
    if (tid < 3) T[tid] = trans[n * 3 + tid];
    __syncthreads();

    const float mn = mask[n];

    // ---- pass 1: logits for all (h, m) ----
    for (int m = tid; m < N_; m += 256) {
        float bias[HH];
        #pragma unroll
        for (int h = 0; h < HH; ++h) bias[h] = bb[h];
        const float4* zp = (const float4*)(z + ((size_t)n * N_ + m) * CZ);
        for (int c4 = 0; c4 < CZ / 4; ++c4) {
            float4 zv = zp[c4];
            const float* wbp = &wb[c4 * 4];
            #pragma unroll
            for (int h = 0; h < HH; ++h) {
                bias[h] += zv.x * wbp[h * CZ + 0] + zv.y * wbp[h * CZ + 1]
                         + zv.z * wbp[h * CZ + 2] + zv.w * wbp[h * CZ + 3];
            }
        }
        float mterm = (mn * mask[m] - 1.0f) * 100000.0f;
        const float* kr  = k  + m * 192;
        const float* kpr = kp + m * 144;
        #pragma unroll
        for (int h = 0; h < HH; ++h) {
            float acc = 0.f;
            #pragma unroll
            for (int c = 0; c < 16; ++c) acc += qv[h * 16 + c] * kr[h * 16 + c];
            acc *= 0.14433756729740643f;            // sqrt(1/48)
            acc += 0.5773502691896258f * bias[h];   // sqrt(1/3)
            float d2 = 0.f;
            #pragma unroll
            for (int p = 0; p < 4; ++p) {
                float dx = qpt[h * 12 + p * 3 + 0] - kpr[h * 12 + p * 3 + 0];
                float dy = qpt[h * 12 + p * 3 + 1] - kpr[h * 12 + p * 3 + 1];
                float dz = qpt[h * 12 + p * 3 + 2] - kpr[h * 12 + p * 3 + 2];
                d2 += dx * dx + dy * dy + dz * dz;
            }
            acc -= 0.5f * hw[h] * d2;
            L[h * N_ + m] = acc + mterm;
        }
    }
    __syncthreads();

    // ---- pass 2: softmax per head; wave w handles heads w, w+4, w+8 ----
    {
        const int wv_ = tid >> 6, lane = tid & 63;
        #pragma unroll
        for (int j = 0; j < 3; ++j) {
            const int h = wv_ + 4 * j;
            float vals[12];
            float mx = -1e30f;
            #pragma unroll
            for (int t = 0; t < 12; ++t) {
                vals[t] = L[h * N_ + lane + 64 * t];
                mx = fmaxf(mx, vals[t]);
            }
            #pragma unroll
            for (int off = 32; off; off >>= 1) mx = fmaxf(mx, __shfl_xor(mx, off));
            float sum = 0.f;
            #pragma unroll
            for (int t = 0; t < 12; ++t) { vals[t] = expf(vals[t] - mx); sum += vals[t]; }
            #pragma unroll
            for (int off = 32; off; off >>= 1) sum += __shfl_xor(sum, off);
            float inv = 1.0f / sum;
            #pragma unroll
            for (int t = 0; t < 12; ++t) L[h * N_ + lane + 64 * t] = vals[t] * inv;
        }
    }
    __syncthreads();

    float* oc = ocat + (size_t)n * 2112;

    // ---- o = a @ v ----
    for (int i = tid; i < 192; i += 256) {
        const float* Lh = L + (i >> 4) * N_;
        float acc = 0.f;
        for (int m = 0; m < N_; ++m) acc += Lh[m] * v[m * 192 + i];
        oc[i] = acc;
    }
    // ---- o_pt global-frame accumulation ----
    for (int i = tid; i < 288; i += 256) {
        const float* Lh = L + (i / 24) * N_;   // h = (i/3)/8
        float acc = 0.f;
        for (int m = 0; m < N_; ++m) acc += Lh[m] * vp[m * 288 + i];
        og[i] = acc;
    }
    // ---- o_pair = a @ z (z streamed again) ----
    {
        const int c = tid & 127, half = tid >> 7;
        float acc[HH];
        #pragma unroll
        for (int h = 0; h < HH; ++h) acc[h] = 0.f;
        const float* zr = z + (size_t)n * N_ * CZ + c;
        const int m0 = half * 384;
        for (int m = m0; m < m0 + 384; ++m) {
            float zz = zr[(size_t)m * CZ];
            #pragma unroll
            for (int h = 0; h < HH; ++h) acc[h] += zz * L[h * N_ + m];
        }
        #pragma unroll
        for (int h = 0; h < HH; ++h) part[(half * HH + h) * CZ + c] = acc[h];
    }
    __syncthreads();

    // ---- inverse rotation + norms ----
    for (int hp = tid; hp < 96; hp += 256) {
        float gx = og[hp * 3 + 0] - T[0];
        float gy = og[hp * 3 + 1] - T[1];
        float gz = og[hp * 3 + 2] - T[2];
        float lx = R[0] * gx + R[3] * gy + R[6] * gz;
        float ly = R[1] * gx + R[4] * gy + R[7] * gz;
        float lz = R[2] * gx + R[5] * gy + R[8] * gz;
        oc[192 + hp] = lx;
        oc[288 + hp] = ly;
        oc[384 + hp] = lz;
        oc[480 + hp] = sqrtf(lx * lx + ly * ly + lz * lz + 1e-8f);
    }
    for (int i = tid; i < HH * CZ; i += 256)
        oc[576 + i] = part[i] + part[HH * CZ + i];
}

// ---------------------------------------------------------------------------
// K3: out[n][j] = o_cat[n,:] . w_out[j,:] + b_out[j]
// ---------------------------------------------------------------------------
__global__ __launch_bounds__(384) void k_final(
    const float* __restrict__ ocat,
    const float* __restrict__ w_out,
    const float* __restrict__ b_out,
    float* __restrict__ out)
{
    const int n = blockIdx.x;
    const int tid = threadIdx.x;
    __shared__ float oc[2112];
    for (int i = tid; i < 2112; i += 384) oc[i] = ocat[(size_t)n * 2112 + i];
    __syncthreads();

    float acc = b_out[tid];
    const float4* w4 = (const float4*)(w_out + (size_t)tid * 2112);
    #pragma unroll 4
    for (int c4 = 0; c4 < 2112 / 4; ++c4) {
        float4 wv = w4[c4];
        const float* sp = &oc[c4 * 4];
        acc += sp[0] * wv.x + sp[1] * wv.y + sp[2] * wv.z + sp[3] * wv.w;
    }
    out[n * 384 + tid] = acc;
}

extern "C" void kernel_launch(void* const* d_in, const int* in_sizes, int n_in,
                              void* d_out, int out_size, void* d_ws, size_t ws_size,
                              hipStream_t stream)
{
    const float* s     = (const float*)d_in[0];
    const float* z     = (const float*)d_in[1];
    const float* rot   = (const float*)d_in[2];
    const float* trans = (const float*)d_in[3];
    const float* mask  = (const float*)d_in[4];
    const float* w_q   = (const float*)d_in[5];
    const float* b_q   = (const float*)d_in[6];
    const float* w_kv  = (const float*)d_in[7];
    const float* b_kv  = (const float*)d_in[8];
    const float* w_qp  = (const float*)d_in[9];
    const float* b_qp  = (const float*)d_in[10];
    const float* w_kvp = (const float*)d_in[11];
    const float* b_kvp = (const float*)d_in[12];
    const float* w_b   = (const float*)d_in[13];
    const float* b_b   = (const float*)d_in[14];
    const float* hwts  = (const float*)d_in[15];
    const float* w_out = (const float*)d_in[16];
    const float* b_out = (const float*)d_in[17];

    float* ws   = (float*)d_ws;
    float* q    = ws;               // 768*192
    float* k    = q  + 147456;      // 768*192
    float* v    = k  + 147456;      // 768*192
    float* qp   = v  + 147456;      // 768*144
    float* kp   = qp + 110592;      // 768*144
    float* vp   = kp + 110592;      // 768*288
    float* ocat = vp + 221184;      // 768*2112
    // total: 2,506,752 floats = 10.0 MB

    k_proj<<<N_, 256, 0, stream>>>(s, rot, trans, w_q, b_q, w_kv, b_kv,
                                   w_qp, b_qp, w_kvp, b_kvp, q, k, v, qp, kp, vp);
    k_fused<<<N_, 256, 0, stream>>>(q, k, v, qp, kp, vp, z, w_b, b_b,
                                    hwts, mask, rot, trans, ocat);
    k_final<<<N_, 384, 0, stream>>>(ocat, w_out, b_out, (float*)d_out);
}